// Round 1
// baseline (985.999 us; speedup 1.0000x reference)
//
#include <hip/hip_runtime.h>
#include <hip/hip_bf16.h>

// GCN 2-layer: N=100000, E=3200000, F 512->16->40, fp32.
// Pipeline: deg(atomic) -> exclusive scan -> CSR fill -> GEMM1 (W-in-regs)
// -> gather1(+relu+bias) -> gather2 -> W2+b2+log_softmax epilogue.
// Key algebra: out = dinv .* segsum(dinv[src]*h[src]) + b ; layer2 aggregation
// done on 16-dim features (aggregate-then-matmul).

#define NF0 512
#define NF1 16
#define NF2 40

// ---------------- CSR construction ----------------

__global__ void k_init(int* __restrict__ deg, int n) {
    int i = blockIdx.x * 256 + threadIdx.x;
    if (i < n) deg[i] = 1;  // self loop
}

__global__ void k_count(const int* __restrict__ dst, int* __restrict__ deg, int E) {
    int e = blockIdx.x * 256 + threadIdx.x;
    if (e < E) atomicAdd(&deg[dst[e]], 1);
}

__global__ void k_bsum(const int* __restrict__ deg, int* __restrict__ bsum, int n) {
    int i = blockIdx.x * 256 + threadIdx.x;
    int v = (i < n) ? (deg[i] - 1) : 0;
    #pragma unroll
    for (int off = 32; off; off >>= 1) v += __shfl_down(v, off, 64);
    __shared__ int ws[4];
    int lane = threadIdx.x & 63, wav = threadIdx.x >> 6;
    if (lane == 0) ws[wav] = v;
    __syncthreads();
    if (threadIdx.x == 0) bsum[blockIdx.x] = ws[0] + ws[1] + ws[2] + ws[3];
}

__global__ void k_bscan(const int* __restrict__ bsum, int* __restrict__ bscan, int nb) {
    __shared__ int s[512];
    int t = threadIdx.x;
    s[t] = (t < nb) ? bsum[t] : 0;
    __syncthreads();
    for (int off = 1; off < 512; off <<= 1) {
        int y = (t >= off) ? s[t - off] : 0;
        __syncthreads();
        s[t] += y;
        __syncthreads();
    }
    if (t < nb) bscan[t] = (t > 0) ? s[t - 1] : 0;
}

__global__ void k_offsets(const int* __restrict__ deg, const int* __restrict__ bscan,
                          int* __restrict__ offs, int* __restrict__ cursor,
                          float* __restrict__ dinv, int n) {
    int i = blockIdx.x * 256 + threadIdx.x;
    int lane = threadIdx.x & 63, wav = threadIdx.x >> 6;
    int v = (i < n) ? (deg[i] - 1) : 0;
    int orig = v;
    #pragma unroll
    for (int off = 1; off < 64; off <<= 1) {
        int y = __shfl_up(v, off, 64);
        if (lane >= off) v += y;
    }
    __shared__ int ws[4];
    if (lane == 63) ws[wav] = v;
    __syncthreads();
    int wadd = 0;
    #pragma unroll
    for (int w = 0; w < 4; ++w) wadd += (w < wav) ? ws[w] : 0;
    if (i < n) {
        int excl = v - orig + wadd + bscan[blockIdx.x];
        offs[i] = excl;
        cursor[i] = excl;
        dinv[i] = rsqrtf((float)deg[i]);
    }
}

__global__ void k_fill(const int* __restrict__ src, const int* __restrict__ dst,
                       int* __restrict__ cursor, int* __restrict__ csr, int E) {
    int e = blockIdx.x * 256 + threadIdx.x;
    if (e < E) {
        int s = src[e];
        int d = dst[e];
        int p = atomicAdd(&cursor[d], 1);
        csr[p] = s;
    }
}

// ---------------- GEMM1: h1s[n][c] = dinv[n] * sum_k x[n][k]*W1[k][c] ----------------
// One wave per row. Lane l owns k in {4l..4l+3} u {256+4l..256+4l+3}; W1 for those
// rows lives in 128 VGPRs (loop-invariant). x row read once, coalesced float4.
// Cross-lane reduction of 16 partials via LDS transpose (stride 17, conflict-free).

__global__ __launch_bounds__(256, 2) void k_gemm1(
    const float* __restrict__ x, const float* __restrict__ W1,
    const float* __restrict__ dinv, float* __restrict__ h1s, int n) {
    __shared__ float red[4 * 64 * 17];
    const int lane = threadIdx.x & 63;
    const int wav = threadIdx.x >> 6;

    float wA[4][16], wB[4][16];
    const float4* W1v = (const float4*)W1;
    #pragma unroll
    for (int j = 0; j < 4; ++j) {
        #pragma unroll
        for (int q = 0; q < 4; ++q) {
            float4 wa = W1v[(4 * lane + j) * 4 + q];
            wA[j][4 * q + 0] = wa.x; wA[j][4 * q + 1] = wa.y;
            wA[j][4 * q + 2] = wa.z; wA[j][4 * q + 3] = wa.w;
            float4 wb = W1v[(256 + 4 * lane + j) * 4 + q];
            wB[j][4 * q + 0] = wb.x; wB[j][4 * q + 1] = wb.y;
            wB[j][4 * q + 2] = wb.z; wB[j][4 * q + 3] = wb.w;
        }
    }

    const float4* xv = (const float4*)x;
    const int gw = blockIdx.x * 4 + wav;
    const int stride = gridDim.x * 4;
    const int iters = (n + stride - 1) / stride;
    int row = gw;
    float4 a0, a1;
    if (row < n) {
        a0 = xv[(size_t)row * 128 + lane];
        a1 = xv[(size_t)row * 128 + 64 + lane];
    }
    float* myred = &red[(wav * 64 + lane) * 17];

    for (int it = 0; it < iters; ++it) {
        float part[16];
        #pragma unroll
        for (int c = 0; c < 16; ++c) part[c] = 0.f;
        if (row < n) {
            float av[4] = {a0.x, a0.y, a0.z, a0.w};
            float bv[4] = {a1.x, a1.y, a1.z, a1.w};
            #pragma unroll
            for (int j = 0; j < 4; ++j) {
                #pragma unroll
                for (int c = 0; c < 16; ++c) {
                    part[c] = fmaf(av[j], wA[j][c], part[c]);
                    part[c] = fmaf(bv[j], wB[j][c], part[c]);
                }
            }
        }
        int nrow = row + stride;
        if (nrow < n) {  // prefetch next row while we reduce
            a0 = xv[(size_t)nrow * 128 + lane];
            a1 = xv[(size_t)nrow * 128 + 64 + lane];
        }
        #pragma unroll
        for (int c = 0; c < 16; ++c) myred[c] = part[c];
        __syncthreads();
        {
            int c = lane & 15, p = lane >> 4;
            const float* base = &red[wav * 64 * 17];
            float s = 0.f;
            #pragma unroll
            for (int i = 0; i < 16; ++i) s += base[(p * 16 + i) * 17 + c];
            s += __shfl_xor(s, 16, 64);
            s += __shfl_xor(s, 32, 64);
            if (row < n && lane < 16) h1s[(size_t)row * 16 + c] = dinv[row] * s;
        }
        __syncthreads();
        row = nrow;
    }
}

// ---------------- Gathers: 16 lanes per node ----------------

__global__ __launch_bounds__(256) void k_gather1(
    const int* __restrict__ offs, const int* __restrict__ ends,
    const int* __restrict__ csr, const float* __restrict__ h1s,
    const float* __restrict__ dinv, const float* __restrict__ b1,
    float* __restrict__ hs2, int n) {
    int t = blockIdx.x * 256 + threadIdx.x;
    int node = t >> 4, c = t & 15;
    if (node >= n) return;
    int j = offs[node], e = ends[node];
    float acc = h1s[(size_t)node * 16 + c];  // self loop
    int idx = (j < e) ? csr[j] : 0;
    while (j < e) {
        int idx2 = (j + 1 < e) ? csr[j + 1] : 0;
        acc += h1s[(size_t)idx * 16 + c];
        idx = idx2;
        ++j;
    }
    float di = dinv[node];
    float v = fmaf(di, acc, b1[c]);
    v = fmaxf(v, 0.f);
    hs2[(size_t)node * 16 + c] = di * v;
}

__global__ __launch_bounds__(256) void k_gather2(
    const int* __restrict__ offs, const int* __restrict__ ends,
    const int* __restrict__ csr, const float* __restrict__ hs2,
    const float* __restrict__ dinv, float* __restrict__ agg2, int n) {
    int t = blockIdx.x * 256 + threadIdx.x;
    int node = t >> 4, c = t & 15;
    if (node >= n) return;
    int j = offs[node], e = ends[node];
    float acc = hs2[(size_t)node * 16 + c];  // self loop
    int idx = (j < e) ? csr[j] : 0;
    while (j < e) {
        int idx2 = (j + 1 < e) ? csr[j + 1] : 0;
        acc += hs2[(size_t)idx * 16 + c];
        idx = idx2;
        ++j;
    }
    agg2[(size_t)node * 16 + c] = dinv[node] * acc;
}

// ---------------- Epilogue: logits = agg2 @ W2 + b2, log_softmax ----------------

__global__ __launch_bounds__(256) void k_final(
    const float* __restrict__ agg2, const float* __restrict__ W2,
    const float* __restrict__ b2, float* __restrict__ out, int n) {
    __shared__ float w2s[NF1 * NF2];
    __shared__ float b2s[NF2];
    for (int i = threadIdx.x; i < NF1 * NF2; i += 256) w2s[i] = W2[i];
    if (threadIdx.x < NF2) b2s[threadIdx.x] = b2[threadIdx.x];
    __syncthreads();
    int wav = threadIdx.x >> 6, lane = threadIdx.x & 63;
    int node = blockIdx.x * 4 + wav;
    if (node >= n) return;
    const float* a = &agg2[(size_t)node * 16];
    float av[16];
    #pragma unroll
    for (int k = 0; k < 16; ++k) av[k] = a[k];
    float d = -1e30f;
    if (lane < NF2) {
        d = b2s[lane];
        #pragma unroll
        for (int k = 0; k < 16; ++k) d = fmaf(av[k], w2s[k * NF2 + lane], d);
    }
    float m = d;
    #pragma unroll
    for (int off = 32; off; off >>= 1) m = fmaxf(m, __shfl_xor(m, off, 64));
    float e = (lane < NF2) ? __expf(d - m) : 0.f;
    float ssum = e;
    #pragma unroll
    for (int off = 32; off; off >>= 1) ssum += __shfl_xor(ssum, off, 64);
    float ls = __logf(ssum);
    if (lane < NF2) out[(size_t)node * NF2 + lane] = d - m - ls;
}

// ---------------- launch ----------------

extern "C" void kernel_launch(void* const* d_in, const int* in_sizes, int n_in,
                              void* d_out, int out_size, void* d_ws, size_t ws_size,
                              hipStream_t stream) {
    const float* x  = (const float*)d_in[0];
    const int*   ei = (const int*)d_in[1];
    const float* W1 = (const float*)d_in[2];
    const float* b1 = (const float*)d_in[3];
    const float* W2 = (const float*)d_in[4];
    const float* b2 = (const float*)d_in[5];
    float* out = (float*)d_out;

    const int N = in_sizes[0] / NF0;  // 100000
    const int E = in_sizes[1] / 2;    // 3200000
    const int* src = ei;
    const int* dst = ei + E;

    char* ws = (char*)d_ws;
    size_t off = 0;
    auto alloc = [&](size_t bytes) -> void* {
        void* p = ws + off;
        off = (off + bytes + 255) & ~(size_t)255;
        return p;
    };
    int*   deg    = (int*)alloc((size_t)N * 4);
    int*   offs   = (int*)alloc((size_t)N * 4);
    int*   cursor = (int*)alloc((size_t)N * 4);
    float* dinv   = (float*)alloc((size_t)N * 4);
    int*   bsum   = (int*)alloc(512 * 4);
    int*   bscan  = (int*)alloc(512 * 4);
    int*   csr    = (int*)alloc((size_t)E * 4);
    float* h1s    = (float*)alloc((size_t)N * NF1 * 4);
    float* hs2    = (float*)alloc((size_t)N * NF1 * 4);
    float* agg2   = h1s;  // h1s dead after gather1; reuse

    const int nb = (N + 255) / 256;   // 391 (fits k_bscan's 512 cap)
    const int eb = (E + 255) / 256;

    k_init   <<<nb, 256, 0, stream>>>(deg, N);
    k_count  <<<eb, 256, 0, stream>>>(dst, deg, E);
    k_bsum   <<<nb, 256, 0, stream>>>(deg, bsum, N);
    k_bscan  <<<1, 512, 0, stream>>>(bsum, bscan, nb);
    k_offsets<<<nb, 256, 0, stream>>>(deg, bscan, offs, cursor, dinv, N);
    k_fill   <<<eb, 256, 0, stream>>>(src, dst, cursor, csr, E);
    k_gemm1  <<<768, 256, 0, stream>>>(x, W1, dinv, h1s, N);
    k_gather1<<<(N * 16 + 255) / 256, 256, 0, stream>>>(offs, cursor, csr, h1s, dinv, b1, hs2, N);
    k_gather2<<<(N * 16 + 255) / 256, 256, 0, stream>>>(offs, cursor, csr, hs2, dinv, agg2, N);
    k_final  <<<(N + 3) / 4, 256, 0, stream>>>(agg2, W2, b2, out, N);
}

// Round 2
// 660.562 us; speedup vs baseline: 1.4927x; 1.4927x over previous
//
#include <hip/hip_runtime.h>
#include <hip/hip_bf16.h>

// GCN 2-layer: N=100000, E=3200000, F 512->16->40, fp32.
// Pipeline: bucket-hist -> scan -> LDS counting-sort binning -> per-bucket CSR
// build -> GEMM1 (W-in-regs) -> gather1(+relu+bias) -> gather2 -> epilogue.
// CSR built via counting sort (no global scatter-atomics): buckets of 128 nodes,
// per-block LDS sort gives coalesced binned writes; per-bucket build keeps csr
// scatter inside a hot 16KB L2 region.

#define NF0 512
#define NF1 16
#define NF2 40
#define BSHIFT 7            // 128 nodes per bucket
#define BNODES 128
#define CHUNK 8192          // edges per binsort block

// ---------------- bucket histogram ----------------

__global__ void k_zero(int* __restrict__ p, int n) {
    int i = blockIdx.x * 256 + threadIdx.x;
    if (i < n) p[i] = 0;
}

__global__ __launch_bounds__(256) void k_hist(const int* __restrict__ dst,
                                              int* __restrict__ bhist, int E, int NB) {
    extern __shared__ int lh[];
    for (int i = threadIdx.x; i < NB; i += 256) lh[i] = 0;
    __syncthreads();
    for (int e = blockIdx.x * 256 + threadIdx.x; e < E; e += gridDim.x * 256)
        atomicAdd(&lh[dst[e] >> BSHIFT], 1);
    __syncthreads();
    for (int i = threadIdx.x; i < NB; i += 256) {
        int c = lh[i];
        if (c) atomicAdd(&bhist[i], c);
    }
}

// single-block scan of NB (<1024) entries -> bstart (exclusive, [NB]=total), cursor init
__global__ __launch_bounds__(1024) void k_scan(const int* __restrict__ bhist,
                                               int* __restrict__ bstart,
                                               int* __restrict__ cursor, int NB) {
    __shared__ int s[1024];
    int t = threadIdx.x;
    s[t] = (t < NB) ? bhist[t] : 0;
    __syncthreads();
    for (int off = 1; off < 1024; off <<= 1) {
        int y = (t >= off) ? s[t - off] : 0;
        __syncthreads();
        s[t] += y;
        __syncthreads();
    }
    if (t < NB) {
        int excl = (t > 0) ? s[t - 1] : 0;
        bstart[t] = excl;
        cursor[t] = excl;
    }
    if (t == NB) bstart[NB] = s[NB - 1];
    if (NB == 1024 && t == 0) bstart[1024] = s[1023];  // unreachable for NB=782
}

// ---------------- binning: counting sort CHUNK edges by bucket in LDS ----------------
// binned[] holds packed (dlow<<20)|src, grouped by bucket (runs reserved per block).

__global__ __launch_bounds__(256) void k_binsort(
    const int* __restrict__ src, const int* __restrict__ dst,
    int* __restrict__ cursor, unsigned int* __restrict__ binned, int E, int NB) {
    __shared__ unsigned int sorted[CHUNK];
    __shared__ unsigned short bid[CHUNK];
    extern __shared__ int dyn[];
    int* hist = dyn;            // NB  (also reused as local cursor)
    int* lstart = dyn + NB;     // NB
    int* gbase = dyn + 2 * NB;  // NB
    __shared__ int wtot[4];

    const int t = threadIdx.x;
    const int lane = t & 63, wav = t >> 6;
    const int base = blockIdx.x * CHUNK;
    const int ne = min(CHUNK, E - base);

    for (int i = t; i < NB; i += 256) hist[i] = 0;
    __syncthreads();

    // Phase A: histogram
    for (int i = t; i < ne; i += 256) atomicAdd(&hist[dst[base + i] >> BSHIFT], 1);
    __syncthreads();

    // Phase B: exclusive scan hist -> lstart (4 entries per thread)
    {
        int eb = t * 4;
        int loc[4];
        int tsum = 0;
        #pragma unroll
        for (int q = 0; q < 4; ++q) {
            loc[q] = (eb + q < NB) ? hist[eb + q] : 0;
            tsum += loc[q];
        }
        int v = tsum;
        #pragma unroll
        for (int off = 1; off < 64; off <<= 1) {
            int y = __shfl_up(v, off, 64);
            if (lane >= off) v += y;
        }
        if (lane == 63) wtot[wav] = v;
        __syncthreads();
        int wbase = 0;
        #pragma unroll
        for (int w = 0; w < 4; ++w) wbase += (w < wav) ? wtot[w] : 0;
        int run = wbase + v - tsum;
        #pragma unroll
        for (int q = 0; q < 4; ++q) {
            if (eb + q < NB) lstart[eb + q] = run;
            run += loc[q];
        }
    }
    __syncthreads();

    // Phase C: reserve global runs; repurpose hist as local cursor
    for (int b = t; b < NB; b += 256) {
        int c = hist[b];
        if (c > 0) gbase[b] = atomicAdd(&cursor[b], c);
        hist[b] = lstart[b];
    }
    __syncthreads();

    // Phase D: scatter into LDS sorted order
    for (int i = t; i < ne; i += 256) {
        int d = dst[base + i];
        int s = src[base + i];
        int b = d >> BSHIFT;
        int pos = atomicAdd(&hist[b], 1);
        sorted[pos] = ((unsigned int)(d & (BNODES - 1)) << 20) | (unsigned int)s;
        bid[pos] = (unsigned short)b;
    }
    __syncthreads();

    // Phase E: coalesced-ish write of grouped runs
    for (int i = t; i < ne; i += 256) {
        int b = bid[i];
        binned[gbase[b] + (i - lstart[b])] = sorted[i];
    }
}

// ---------------- per-bucket CSR build ----------------
// one block per bucket: node histogram, scan, deg/dinv/offs/ends, local csr scatter

__global__ __launch_bounds__(256) void k_build(
    const unsigned int* __restrict__ binned, const int* __restrict__ bstart,
    int* __restrict__ csr, int* __restrict__ offs, int* __restrict__ ends,
    float* __restrict__ dinv, int n) {
    __shared__ int cnt[BNODES];
    __shared__ int lcur[BNODES];
    __shared__ int excl[BNODES];
    const int b = blockIdx.x;
    const int t = threadIdx.x;
    const int lane = t & 63, wav = t >> 6;
    const int s0 = bstart[b], s1 = bstart[b + 1];
    const int ne = s1 - s0;

    if (t < BNODES) cnt[t] = 0;
    __syncthreads();
    for (int i = t; i < ne; i += 256)
        atomicAdd(&cnt[(binned[s0 + i] >> 20) & (BNODES - 1)], 1);
    __syncthreads();

    if (wav == 0) {  // 2 counters per lane, wave scan
        int c0 = cnt[2 * lane], c1 = cnt[2 * lane + 1];
        int v = c0 + c1;
        #pragma unroll
        for (int off = 1; off < 64; off <<= 1) {
            int y = __shfl_up(v, off, 64);
            if (lane >= off) v += y;
        }
        int ex = v - c0 - c1;
        excl[2 * lane] = ex;
        excl[2 * lane + 1] = ex + c0;
        lcur[2 * lane] = ex;
        lcur[2 * lane + 1] = ex + c0;
    }
    __syncthreads();

    if (t < BNODES) {
        int node = b * BNODES + t;
        if (node < n) {
            int deg = cnt[t] + 1;  // + self loop
            dinv[node] = rsqrtf((float)deg);
            int o = s0 + excl[t];
            offs[node] = o;
            ends[node] = o + cnt[t];
        }
    }
    __syncthreads();

    for (int i = t; i < ne; i += 256) {
        unsigned int v = binned[s0 + i];
        int dlow = (v >> 20) & (BNODES - 1);
        int p = atomicAdd(&lcur[dlow], 1);
        csr[s0 + p] = (int)(v & 0xFFFFFu);
    }
}

// ---------------- GEMM1: h1s[n][c] = dinv[n] * sum_k x[n][k]*W1[k][c] ----------------

__global__ __launch_bounds__(256, 2) void k_gemm1(
    const float* __restrict__ x, const float* __restrict__ W1,
    const float* __restrict__ dinv, float* __restrict__ h1s, int n) {
    __shared__ float red[4 * 64 * 17];
    const int lane = threadIdx.x & 63;
    const int wav = threadIdx.x >> 6;

    float wA[4][16], wB[4][16];
    const float4* W1v = (const float4*)W1;
    #pragma unroll
    for (int j = 0; j < 4; ++j) {
        #pragma unroll
        for (int q = 0; q < 4; ++q) {
            float4 wa = W1v[(4 * lane + j) * 4 + q];
            wA[j][4 * q + 0] = wa.x; wA[j][4 * q + 1] = wa.y;
            wA[j][4 * q + 2] = wa.z; wA[j][4 * q + 3] = wa.w;
            float4 wb = W1v[(256 + 4 * lane + j) * 4 + q];
            wB[j][4 * q + 0] = wb.x; wB[j][4 * q + 1] = wb.y;
            wB[j][4 * q + 2] = wb.z; wB[j][4 * q + 3] = wb.w;
        }
    }

    const float4* xv = (const float4*)x;
    const int gw = blockIdx.x * 4 + wav;
    const int stride = gridDim.x * 4;
    const int iters = (n + stride - 1) / stride;
    int row = gw;
    float4 a0, a1;
    if (row < n) {
        a0 = xv[(size_t)row * 128 + lane];
        a1 = xv[(size_t)row * 128 + 64 + lane];
    }
    float* myred = &red[(wav * 64 + lane) * 17];

    for (int it = 0; it < iters; ++it) {
        float part[16];
        #pragma unroll
        for (int c = 0; c < 16; ++c) part[c] = 0.f;
        if (row < n) {
            float av[4] = {a0.x, a0.y, a0.z, a0.w};
            float bv[4] = {a1.x, a1.y, a1.z, a1.w};
            #pragma unroll
            for (int j = 0; j < 4; ++j) {
                #pragma unroll
                for (int c = 0; c < 16; ++c) {
                    part[c] = fmaf(av[j], wA[j][c], part[c]);
                    part[c] = fmaf(bv[j], wB[j][c], part[c]);
                }
            }
        }
        int nrow = row + stride;
        if (nrow < n) {  // prefetch next row while we reduce
            a0 = xv[(size_t)nrow * 128 + lane];
            a1 = xv[(size_t)nrow * 128 + 64 + lane];
        }
        #pragma unroll
        for (int c = 0; c < 16; ++c) myred[c] = part[c];
        __syncthreads();
        {
            int c = lane & 15, p = lane >> 4;
            const float* base = &red[wav * 64 * 17];
            float s = 0.f;
            #pragma unroll
            for (int i = 0; i < 16; ++i) s += base[(p * 16 + i) * 17 + c];
            s += __shfl_xor(s, 16, 64);
            s += __shfl_xor(s, 32, 64);
            if (row < n && lane < 16) h1s[(size_t)row * 16 + c] = dinv[row] * s;
        }
        __syncthreads();
        row = nrow;
    }
}

// ---------------- Gathers: 16 lanes per node ----------------

__global__ __launch_bounds__(256) void k_gather1(
    const int* __restrict__ offs, const int* __restrict__ ends,
    const int* __restrict__ csr, const float* __restrict__ h1s,
    const float* __restrict__ dinv, const float* __restrict__ b1,
    float* __restrict__ hs2, int n) {
    int t = blockIdx.x * 256 + threadIdx.x;
    int node = t >> 4, c = t & 15;
    if (node >= n) return;
    int j = offs[node], e = ends[node];
    float acc = h1s[(size_t)node * 16 + c];  // self loop
    int idx = (j < e) ? csr[j] : 0;
    while (j < e) {
        int idx2 = (j + 1 < e) ? csr[j + 1] : 0;
        acc += h1s[(size_t)idx * 16 + c];
        idx = idx2;
        ++j;
    }
    float di = dinv[node];
    float v = fmaf(di, acc, b1[c]);
    v = fmaxf(v, 0.f);
    hs2[(size_t)node * 16 + c] = di * v;
}

__global__ __launch_bounds__(256) void k_gather2(
    const int* __restrict__ offs, const int* __restrict__ ends,
    const int* __restrict__ csr, const float* __restrict__ hs2,
    const float* __restrict__ dinv, float* __restrict__ agg2, int n) {
    int t = blockIdx.x * 256 + threadIdx.x;
    int node = t >> 4, c = t & 15;
    if (node >= n) return;
    int j = offs[node], e = ends[node];
    float acc = hs2[(size_t)node * 16 + c];  // self loop
    int idx = (j < e) ? csr[j] : 0;
    while (j < e) {
        int idx2 = (j + 1 < e) ? csr[j + 1] : 0;
        acc += hs2[(size_t)idx * 16 + c];
        idx = idx2;
        ++j;
    }
    agg2[(size_t)node * 16 + c] = dinv[node] * acc;
}

// ---------------- Epilogue: logits = agg2 @ W2 + b2, log_softmax ----------------

__global__ __launch_bounds__(256) void k_final(
    const float* __restrict__ agg2, const float* __restrict__ W2,
    const float* __restrict__ b2, float* __restrict__ out, int n) {
    __shared__ float w2s[NF1 * NF2];
    __shared__ float b2s[NF2];
    for (int i = threadIdx.x; i < NF1 * NF2; i += 256) w2s[i] = W2[i];
    if (threadIdx.x < NF2) b2s[threadIdx.x] = b2[threadIdx.x];
    __syncthreads();
    int wav = threadIdx.x >> 6, lane = threadIdx.x & 63;
    int node = blockIdx.x * 4 + wav;
    if (node >= n) return;
    const float* a = &agg2[(size_t)node * 16];
    float av[16];
    #pragma unroll
    for (int k = 0; k < 16; ++k) av[k] = a[k];
    float d = -1e30f;
    if (lane < NF2) {
        d = b2s[lane];
        #pragma unroll
        for (int k = 0; k < 16; ++k) d = fmaf(av[k], w2s[k * NF2 + lane], d);
    }
    float m = d;
    #pragma unroll
    for (int off = 32; off; off >>= 1) m = fmaxf(m, __shfl_xor(m, off, 64));
    float e = (lane < NF2) ? __expf(d - m) : 0.f;
    float ssum = e;
    #pragma unroll
    for (int off = 32; off; off >>= 1) ssum += __shfl_xor(ssum, off, 64);
    float ls = __logf(ssum);
    if (lane < NF2) out[(size_t)node * NF2 + lane] = d - m - ls;
}

// ---------------- launch ----------------

extern "C" void kernel_launch(void* const* d_in, const int* in_sizes, int n_in,
                              void* d_out, int out_size, void* d_ws, size_t ws_size,
                              hipStream_t stream) {
    const float* x  = (const float*)d_in[0];
    const int*   ei = (const int*)d_in[1];
    const float* W1 = (const float*)d_in[2];
    const float* b1 = (const float*)d_in[3];
    const float* W2 = (const float*)d_in[4];
    const float* b2 = (const float*)d_in[5];
    float* out = (float*)d_out;

    const int N = in_sizes[0] / NF0;  // 100000
    const int E = in_sizes[1] / 2;    // 3200000
    const int NB = (N + BNODES - 1) / BNODES;  // 782
    const int* src = ei;
    const int* dst = ei + E;

    char* ws = (char*)d_ws;
    size_t off = 0;
    auto alloc = [&](size_t bytes) -> void* {
        void* p = ws + off;
        off = (off + bytes + 255) & ~(size_t)255;
        return p;
    };
    int*   bhist  = (int*)alloc((size_t)NB * 4);
    int*   bstart = (int*)alloc((size_t)(NB + 1) * 4);
    int*   cursor = (int*)alloc((size_t)NB * 4);
    unsigned int* binned = (unsigned int*)alloc((size_t)E * 4);
    int*   csr    = (int*)alloc((size_t)E * 4);
    int*   offs   = (int*)alloc((size_t)N * 4);
    int*   ends   = (int*)alloc((size_t)N * 4);
    float* dinv   = (float*)alloc((size_t)N * 4);
    // binned is dead after k_build: reuse its 12.8MB for h1s/hs2 (6.4MB each)
    float* h1s = (float*)binned;
    float* hs2 = (float*)binned + (size_t)N * NF1;
    float* agg2 = h1s;  // h1s dead after gather1

    const int eb = (E + CHUNK - 1) / CHUNK;  // 391
    const size_t histBytes = (size_t)NB * 4;

    k_zero   <<<(NB + 255) / 256, 256, 0, stream>>>(bhist, NB);
    k_hist   <<<512, 256, histBytes, stream>>>(dst, bhist, E, NB);
    k_scan   <<<1, 1024, 0, stream>>>(bhist, bstart, cursor, NB);
    k_binsort<<<eb, 256, 3 * histBytes, stream>>>(src, dst, cursor, binned, E, NB);
    k_build  <<<NB, 256, 0, stream>>>(binned, bstart, csr, offs, ends, dinv, N);
    k_gemm1  <<<768, 256, 0, stream>>>(x, W1, dinv, h1s, N);
    k_gather1<<<(N * 16 + 255) / 256, 256, 0, stream>>>(offs, ends, csr, h1s, dinv, b1, hs2, N);
    k_gather2<<<(N * 16 + 255) / 256, 256, 0, stream>>>(offs, ends, csr, hs2, dinv, agg2, N);
    k_final  <<<(N + 3) / 4, 256, 0, stream>>>(agg2, W2, b2, out, N);
}

// Round 3
// 492.133 us; speedup vs baseline: 2.0035x; 1.3422x over previous
//
#include <hip/hip_runtime.h>
#include <hip/hip_bf16.h>

// GCN 2-layer: N=100000, E=3200000, F 512->16->40, fp32.
// Pipeline: bucket-hist -> scan -> LDS counting-sort binning -> per-bucket CSR
// build -> GEMM1 (W-in-regs, shuffle-butterfly reduce, barrier-free) ->
// gather1(+relu+bias, 4-wide) -> fused gather2+W2+log_softmax.

#define NF0 512
#define NF1 16
#define NF2 40
#define BSHIFT 7            // 128 nodes per bucket
#define BNODES 128
#define CHUNK 8192          // edges per binsort block

// ---------------- bucket histogram ----------------

__global__ void k_zero(int* __restrict__ p, int n) {
    int i = blockIdx.x * 256 + threadIdx.x;
    if (i < n) p[i] = 0;
}

__global__ __launch_bounds__(256) void k_hist(const int* __restrict__ dst,
                                              int* __restrict__ bhist, int E, int NB) {
    extern __shared__ int lh[];
    for (int i = threadIdx.x; i < NB; i += 256) lh[i] = 0;
    __syncthreads();
    for (int e = blockIdx.x * 256 + threadIdx.x; e < E; e += gridDim.x * 256)
        atomicAdd(&lh[dst[e] >> BSHIFT], 1);
    __syncthreads();
    for (int i = threadIdx.x; i < NB; i += 256) {
        int c = lh[i];
        if (c) atomicAdd(&bhist[i], c);
    }
}

__global__ __launch_bounds__(1024) void k_scan(const int* __restrict__ bhist,
                                               int* __restrict__ bstart,
                                               int* __restrict__ cursor, int NB) {
    __shared__ int s[1024];
    int t = threadIdx.x;
    s[t] = (t < NB) ? bhist[t] : 0;
    __syncthreads();
    for (int off = 1; off < 1024; off <<= 1) {
        int y = (t >= off) ? s[t - off] : 0;
        __syncthreads();
        s[t] += y;
        __syncthreads();
    }
    if (t < NB) {
        int excl = (t > 0) ? s[t - 1] : 0;
        bstart[t] = excl;
        cursor[t] = excl;
    }
    if (t == NB) bstart[NB] = s[NB - 1];
}

// ---------------- binning: counting sort CHUNK edges by bucket in LDS ----------------

__global__ __launch_bounds__(256) void k_binsort(
    const int* __restrict__ src, const int* __restrict__ dst,
    int* __restrict__ cursor, unsigned int* __restrict__ binned, int E, int NB) {
    __shared__ unsigned int sorted[CHUNK];
    __shared__ unsigned short bid[CHUNK];
    extern __shared__ int dyn[];
    int* hist = dyn;            // NB (reused as local cursor)
    int* lstart = dyn + NB;     // NB
    int* gbase = dyn + 2 * NB;  // NB
    __shared__ int wtot[4];

    const int t = threadIdx.x;
    const int lane = t & 63, wav = t >> 6;
    const int base = blockIdx.x * CHUNK;
    const int ne = min(CHUNK, E - base);

    for (int i = t; i < NB; i += 256) hist[i] = 0;
    __syncthreads();

    for (int i = t; i < ne; i += 256) atomicAdd(&hist[dst[base + i] >> BSHIFT], 1);
    __syncthreads();

    {
        int eb = t * 4;
        int loc[4];
        int tsum = 0;
        #pragma unroll
        for (int q = 0; q < 4; ++q) {
            loc[q] = (eb + q < NB) ? hist[eb + q] : 0;
            tsum += loc[q];
        }
        int v = tsum;
        #pragma unroll
        for (int off = 1; off < 64; off <<= 1) {
            int y = __shfl_up(v, off, 64);
            if (lane >= off) v += y;
        }
        if (lane == 63) wtot[wav] = v;
        __syncthreads();
        int wbase = 0;
        #pragma unroll
        for (int w = 0; w < 4; ++w) wbase += (w < wav) ? wtot[w] : 0;
        int run = wbase + v - tsum;
        #pragma unroll
        for (int q = 0; q < 4; ++q) {
            if (eb + q < NB) lstart[eb + q] = run;
            run += loc[q];
        }
    }
    __syncthreads();

    for (int b = t; b < NB; b += 256) {
        int c = hist[b];
        if (c > 0) gbase[b] = atomicAdd(&cursor[b], c);
        hist[b] = lstart[b];
    }
    __syncthreads();

    for (int i = t; i < ne; i += 256) {
        int d = dst[base + i];
        int s = src[base + i];
        int b = d >> BSHIFT;
        int pos = atomicAdd(&hist[b], 1);
        sorted[pos] = ((unsigned int)(d & (BNODES - 1)) << 20) | (unsigned int)s;
        bid[pos] = (unsigned short)b;
    }
    __syncthreads();

    for (int i = t; i < ne; i += 256) {
        int b = bid[i];
        binned[gbase[b] + (i - lstart[b])] = sorted[i];
    }
}

// ---------------- per-bucket CSR build ----------------

__global__ __launch_bounds__(256) void k_build(
    const unsigned int* __restrict__ binned, const int* __restrict__ bstart,
    int* __restrict__ csr, int* __restrict__ offs, int* __restrict__ ends,
    float* __restrict__ dinv, int n) {
    __shared__ int cnt[BNODES];
    __shared__ int lcur[BNODES];
    __shared__ int excl[BNODES];
    const int b = blockIdx.x;
    const int t = threadIdx.x;
    const int lane = t & 63, wav = t >> 6;
    const int s0 = bstart[b], s1 = bstart[b + 1];
    const int ne = s1 - s0;

    if (t < BNODES) cnt[t] = 0;
    __syncthreads();
    for (int i = t; i < ne; i += 256)
        atomicAdd(&cnt[(binned[s0 + i] >> 20) & (BNODES - 1)], 1);
    __syncthreads();

    if (wav == 0) {
        int c0 = cnt[2 * lane], c1 = cnt[2 * lane + 1];
        int v = c0 + c1;
        #pragma unroll
        for (int off = 1; off < 64; off <<= 1) {
            int y = __shfl_up(v, off, 64);
            if (lane >= off) v += y;
        }
        int ex = v - c0 - c1;
        excl[2 * lane] = ex;
        excl[2 * lane + 1] = ex + c0;
        lcur[2 * lane] = ex;
        lcur[2 * lane + 1] = ex + c0;
    }
    __syncthreads();

    if (t < BNODES) {
        int node = b * BNODES + t;
        if (node < n) {
            int deg = cnt[t] + 1;  // + self loop
            dinv[node] = rsqrtf((float)deg);
            int o = s0 + excl[t];
            offs[node] = o;
            ends[node] = o + cnt[t];
        }
    }
    __syncthreads();

    for (int i = t; i < ne; i += 256) {
        unsigned int v = binned[s0 + i];
        int dlow = (v >> 20) & (BNODES - 1);
        int p = atomicAdd(&lcur[dlow], 1);
        csr[s0 + p] = (int)(v & 0xFFFFFu);
    }
}

// ---------------- GEMM1: h1s[n][c] = dinv[n] * sum_k x[n][k]*W1[k][c] ----------------
// One wave per row, barrier-free. Lane l owns k in {4l..4l+3} u {256+4l..256+4l+3};
// W1 in 128 VGPRs. 16 partials reduced by shuffle butterfly (no LDS, no syncthreads).
// 2-deep row prefetch: ~4KB in flight per wave.

__global__ __launch_bounds__(256, 2) void k_gemm1(
    const float* __restrict__ x, const float* __restrict__ W1,
    const float* __restrict__ dinv, float* __restrict__ h1s, int n) {
    const int lane = threadIdx.x & 63;
    const int wav = threadIdx.x >> 6;

    float wA[4][16], wB[4][16];
    const float4* W1v = (const float4*)W1;
    #pragma unroll
    for (int j = 0; j < 4; ++j) {
        #pragma unroll
        for (int q = 0; q < 4; ++q) {
            float4 wa = W1v[(4 * lane + j) * 4 + q];
            wA[j][4 * q + 0] = wa.x; wA[j][4 * q + 1] = wa.y;
            wA[j][4 * q + 2] = wa.z; wA[j][4 * q + 3] = wa.w;
            float4 wb = W1v[(256 + 4 * lane + j) * 4 + q];
            wB[j][4 * q + 0] = wb.x; wB[j][4 * q + 1] = wb.y;
            wB[j][4 * q + 2] = wb.z; wB[j][4 * q + 3] = wb.w;
        }
    }

    const float4* xv = (const float4*)x;
    const int stride = gridDim.x * 4;

    auto process = [&](float4 p0, float4 p1, int r) {
        float part[16];
        #pragma unroll
        for (int c = 0; c < 16; ++c) part[c] = 0.f;
        float av[8] = {p0.x, p0.y, p0.z, p0.w, p1.x, p1.y, p1.z, p1.w};
        #pragma unroll
        for (int j = 0; j < 4; ++j) {
            #pragma unroll
            for (int c = 0; c < 16; ++c) {
                part[c] = fmaf(av[j], wA[j][c], part[c]);
                part[c] = fmaf(av[4 + j], wB[j][c], part[c]);
            }
        }
        // butterfly: after stage k the value's column gains bit from lane
        const bool h5 = (lane & 32) != 0;
        float v8[8];
        #pragma unroll
        for (int j = 0; j < 8; ++j)
            v8[j] = (h5 ? part[j + 8] : part[j]) +
                    __shfl_xor(h5 ? part[j] : part[j + 8], 32, 64);
        const bool h4 = (lane & 16) != 0;
        float v4[4];
        #pragma unroll
        for (int j = 0; j < 4; ++j)
            v4[j] = (h4 ? v8[j + 4] : v8[j]) +
                    __shfl_xor(h4 ? v8[j] : v8[j + 4], 16, 64);
        const bool h3 = (lane & 8) != 0;
        float v2[2];
        #pragma unroll
        for (int j = 0; j < 2; ++j)
            v2[j] = (h3 ? v4[j + 2] : v4[j]) +
                    __shfl_xor(h3 ? v4[j] : v4[j + 2], 8, 64);
        const bool h2 = (lane & 4) != 0;
        float v1 = (h2 ? v2[1] : v2[0]) +
                   __shfl_xor(h2 ? v2[0] : v2[1], 4, 64);
        v1 += __shfl_xor(v1, 2, 64);
        v1 += __shfl_xor(v1, 1, 64);
        // lane 4c now holds column c = lane>>2
        if ((lane & 3) == 0)
            h1s[(size_t)r * 16 + (lane >> 2)] = dinv[r] * v1;
    };

    int r0 = blockIdx.x * 4 + wav;
    int r1 = r0 + stride;
    float4 a0, a1, b0, b1;
    if (r0 < n) {
        a0 = xv[(size_t)r0 * 128 + lane];
        a1 = xv[(size_t)r0 * 128 + 64 + lane];
    }
    if (r1 < n) {
        b0 = xv[(size_t)r1 * 128 + lane];
        b1 = xv[(size_t)r1 * 128 + 64 + lane];
    }

    while (r0 < n) {
        float4 ca0 = a0, ca1 = a1;
        int pr = r0 + 2 * stride;
        if (pr < n) {  // prefetch 2 ahead while computing
            a0 = xv[(size_t)pr * 128 + lane];
            a1 = xv[(size_t)pr * 128 + 64 + lane];
        }
        process(ca0, ca1, r0);
        if (r1 < n) {
            float4 cb0 = b0, cb1 = b1;
            int pr2 = r1 + 2 * stride;
            if (pr2 < n) {
                b0 = xv[(size_t)pr2 * 128 + lane];
                b1 = xv[(size_t)pr2 * 128 + 64 + lane];
            }
            process(cb0, cb1, r1);
        }
        r0 += 2 * stride;
        r1 += 2 * stride;
    }
}

// ---------------- gather1: 16 lanes/node, 4-wide MLP ----------------

__global__ __launch_bounds__(256) void k_gather1(
    const int* __restrict__ offs, const int* __restrict__ ends,
    const int* __restrict__ csr, const float* __restrict__ h1s,
    const float* __restrict__ dinv, const float* __restrict__ b1,
    float* __restrict__ hs2, int n) {
    int t = blockIdx.x * 256 + threadIdx.x;
    int node = t >> 4, c = t & 15;
    if (node >= n) return;
    int j = offs[node], e = ends[node];
    float acc0 = h1s[(size_t)node * 16 + c];  // self loop
    float acc1 = 0.f, acc2 = 0.f, acc3 = 0.f;
    for (; j + 3 < e; j += 4) {
        int i0 = csr[j], i1 = csr[j + 1], i2 = csr[j + 2], i3 = csr[j + 3];
        acc0 += h1s[(size_t)i0 * 16 + c];
        acc1 += h1s[(size_t)i1 * 16 + c];
        acc2 += h1s[(size_t)i2 * 16 + c];
        acc3 += h1s[(size_t)i3 * 16 + c];
    }
    for (; j < e; ++j) acc0 += h1s[(size_t)csr[j] * 16 + c];
    float acc = (acc0 + acc1) + (acc2 + acc3);
    float di = dinv[node];
    float v = fmaf(di, acc, b1[c]);
    hs2[(size_t)node * 16 + c] = di * fmaxf(v, 0.f);
}

// ---------------- fused gather2 + W2 + b2 + log_softmax ----------------

__global__ __launch_bounds__(256) void k_g2f(
    const int* __restrict__ offs, const int* __restrict__ ends,
    const int* __restrict__ csr, const float* __restrict__ hs2,
    const float* __restrict__ dinv, const float* __restrict__ W2,
    const float* __restrict__ b2, float* __restrict__ out, int n) {
    __shared__ float w2s[NF1 * NF2];
    __shared__ float b2s[NF2];
    __shared__ float agg[16][17];
    for (int i = threadIdx.x; i < NF1 * NF2; i += 256) w2s[i] = W2[i];
    if (threadIdx.x < NF2) b2s[threadIdx.x] = b2[threadIdx.x];

    int t = blockIdx.x * 256 + threadIdx.x;
    int node = t >> 4, c = t & 15;
    int g = threadIdx.x >> 4;
    float acc = 0.f;
    if (node < n) {
        int j = offs[node], e = ends[node];
        float acc0 = hs2[(size_t)node * 16 + c];  // self loop
        float acc1 = 0.f, acc2 = 0.f, acc3 = 0.f;
        for (; j + 3 < e; j += 4) {
            int i0 = csr[j], i1 = csr[j + 1], i2 = csr[j + 2], i3 = csr[j + 3];
            acc0 += hs2[(size_t)i0 * 16 + c];
            acc1 += hs2[(size_t)i1 * 16 + c];
            acc2 += hs2[(size_t)i2 * 16 + c];
            acc3 += hs2[(size_t)i3 * 16 + c];
        }
        for (; j < e; ++j) acc0 += hs2[(size_t)csr[j] * 16 + c];
        acc = ((acc0 + acc1) + (acc2 + acc3)) * dinv[node];
    }
    agg[g][c] = acc;
    __syncthreads();

    int wav = threadIdx.x >> 6, lane = threadIdx.x & 63;
    int nbase = blockIdx.x * 16 + wav * 4;
    #pragma unroll
    for (int q = 0; q < 4; ++q) {
        int nd = nbase + q;
        if (nd >= n) break;  // nd uniform across wave
        float av[16];
        #pragma unroll
        for (int k = 0; k < 16; ++k) av[k] = agg[wav * 4 + q][k];
        float d = -1e30f;
        if (lane < NF2) {
            d = b2s[lane];
            #pragma unroll
            for (int k = 0; k < 16; ++k) d = fmaf(av[k], w2s[k * NF2 + lane], d);
        }
        float m = d;
        #pragma unroll
        for (int off = 32; off; off >>= 1) m = fmaxf(m, __shfl_xor(m, off, 64));
        float e2 = (lane < NF2) ? __expf(d - m) : 0.f;
        float ssum = e2;
        #pragma unroll
        for (int off = 32; off; off >>= 1) ssum += __shfl_xor(ssum, off, 64);
        float ls = __logf(ssum);
        if (lane < NF2) out[(size_t)nd * NF2 + lane] = d - m - ls;
    }
}

// ---------------- launch ----------------

extern "C" void kernel_launch(void* const* d_in, const int* in_sizes, int n_in,
                              void* d_out, int out_size, void* d_ws, size_t ws_size,
                              hipStream_t stream) {
    const float* x  = (const float*)d_in[0];
    const int*   ei = (const int*)d_in[1];
    const float* W1 = (const float*)d_in[2];
    const float* b1 = (const float*)d_in[3];
    const float* W2 = (const float*)d_in[4];
    const float* b2 = (const float*)d_in[5];
    float* out = (float*)d_out;

    const int N = in_sizes[0] / NF0;  // 100000
    const int E = in_sizes[1] / 2;    // 3200000
    const int NB = (N + BNODES - 1) / BNODES;  // 782
    const int* src = ei;
    const int* dst = ei + E;

    char* ws = (char*)d_ws;
    size_t off = 0;
    auto alloc = [&](size_t bytes) -> void* {
        void* p = ws + off;
        off = (off + bytes + 255) & ~(size_t)255;
        return p;
    };
    int*   bhist  = (int*)alloc((size_t)NB * 4);
    int*   bstart = (int*)alloc((size_t)(NB + 1) * 4);
    int*   cursor = (int*)alloc((size_t)NB * 4);
    unsigned int* binned = (unsigned int*)alloc((size_t)E * 4);
    int*   csr    = (int*)alloc((size_t)E * 4);
    int*   offs   = (int*)alloc((size_t)N * 4);
    int*   ends   = (int*)alloc((size_t)N * 4);
    float* dinv   = (float*)alloc((size_t)N * 4);
    // binned dead after k_build: reuse for h1s/hs2 (6.4MB each)
    float* h1s = (float*)binned;
    float* hs2 = (float*)binned + (size_t)N * NF1;

    const int eb = (E + CHUNK - 1) / CHUNK;  // 391
    const size_t histBytes = (size_t)NB * 4;

    k_zero   <<<(NB + 255) / 256, 256, 0, stream>>>(bhist, NB);
    k_hist   <<<512, 256, histBytes, stream>>>(dst, bhist, E, NB);
    k_scan   <<<1, 1024, 0, stream>>>(bhist, bstart, cursor, NB);
    k_binsort<<<eb, 256, 3 * histBytes, stream>>>(src, dst, cursor, binned, E, NB);
    k_build  <<<NB, 256, 0, stream>>>(binned, bstart, csr, offs, ends, dinv, N);
    k_gemm1  <<<1024, 256, 0, stream>>>(x, W1, dinv, h1s, N);
    k_gather1<<<(N * 16 + 255) / 256, 256, 0, stream>>>(offs, ends, csr, h1s, dinv, b1, hs2, N);
    k_g2f    <<<(N * 16 + 255) / 256, 256, 0, stream>>>(offs, ends, csr, hs2, dinv, W2, b2, out, N);
}

// Round 4
// 471.063 us; speedup vs baseline: 2.0931x; 1.0447x over previous
//
#include <hip/hip_runtime.h>
#include <hip/hip_bf16.h>

// GCN 2-layer: N=100000, E=3200000, F 512->16->40, fp32 in/out.
// Pipeline: bucket-hist -> scan -> LDS counting-sort binning -> per-bucket CSR
// build -> GEMM1 (W-in-regs, shuffle butterfly, bf16 out) ->
// gather1(+relu+bias, bf16 table, 8 lanes/node) -> fused gather2+W2+log_softmax.
// bf16 tables: 3.2MB/node-table fits per-XCD L2 (4MB); halves gather traffic.

#define NF0 512
#define NF1 16
#define NF2 40
#define BSHIFT 7            // 128 nodes per bucket
#define BNODES 128
#define CHUNK 8192          // edges per binsort block

// bf16 pair helpers: uint u = bf16(lo) | bf16(hi)<<16
__device__ __forceinline__ float bflo(unsigned int u) { return __uint_as_float(u << 16); }
__device__ __forceinline__ float bfhi(unsigned int u) { return __uint_as_float(u & 0xFFFF0000u); }
__device__ __forceinline__ unsigned int packbf(float lo, float hi) {
    unsigned int bl = __float_as_uint(lo);
    bl = (bl + 0x7FFFu + ((bl >> 16) & 1u)) >> 16;
    unsigned int bh = __float_as_uint(hi);
    bh = (bh + 0x7FFFu + ((bh >> 16) & 1u)) & 0xFFFF0000u;
    return bl | bh;
}

// ---------------- bucket histogram ----------------

__global__ void k_zero(int* __restrict__ p, int n) {
    int i = blockIdx.x * 256 + threadIdx.x;
    if (i < n) p[i] = 0;
}

__global__ __launch_bounds__(256) void k_hist(const int* __restrict__ dst,
                                              int* __restrict__ bhist, int E, int NB) {
    extern __shared__ int lh[];
    for (int i = threadIdx.x; i < NB; i += 256) lh[i] = 0;
    __syncthreads();
    for (int e = blockIdx.x * 256 + threadIdx.x; e < E; e += gridDim.x * 256)
        atomicAdd(&lh[dst[e] >> BSHIFT], 1);
    __syncthreads();
    for (int i = threadIdx.x; i < NB; i += 256) {
        int c = lh[i];
        if (c) atomicAdd(&bhist[i], c);
    }
}

__global__ __launch_bounds__(1024) void k_scan(const int* __restrict__ bhist,
                                               int* __restrict__ bstart,
                                               int* __restrict__ cursor, int NB) {
    __shared__ int s[1024];
    int t = threadIdx.x;
    s[t] = (t < NB) ? bhist[t] : 0;
    __syncthreads();
    for (int off = 1; off < 1024; off <<= 1) {
        int y = (t >= off) ? s[t - off] : 0;
        __syncthreads();
        s[t] += y;
        __syncthreads();
    }
    if (t < NB) {
        int excl = (t > 0) ? s[t - 1] : 0;
        bstart[t] = excl;
        cursor[t] = excl;
    }
    if (t == NB) bstart[NB] = s[NB - 1];
}

// ---------------- binning: counting sort CHUNK edges by bucket in LDS ----------------

__global__ __launch_bounds__(256) void k_binsort(
    const int* __restrict__ src, const int* __restrict__ dst,
    int* __restrict__ cursor, unsigned int* __restrict__ binned, int E, int NB) {
    __shared__ unsigned int sorted[CHUNK];
    __shared__ unsigned short bid[CHUNK];
    extern __shared__ int dyn[];
    int* hist = dyn;            // NB (reused as local cursor)
    int* lstart = dyn + NB;     // NB
    int* gbase = dyn + 2 * NB;  // NB
    __shared__ int wtot[4];

    const int t = threadIdx.x;
    const int lane = t & 63, wav = t >> 6;
    const int base = blockIdx.x * CHUNK;
    const int ne = min(CHUNK, E - base);

    for (int i = t; i < NB; i += 256) hist[i] = 0;
    __syncthreads();

    for (int i = t; i < ne; i += 256) atomicAdd(&hist[dst[base + i] >> BSHIFT], 1);
    __syncthreads();

    {
        int eb = t * 4;
        int loc[4];
        int tsum = 0;
        #pragma unroll
        for (int q = 0; q < 4; ++q) {
            loc[q] = (eb + q < NB) ? hist[eb + q] : 0;
            tsum += loc[q];
        }
        int v = tsum;
        #pragma unroll
        for (int off = 1; off < 64; off <<= 1) {
            int y = __shfl_up(v, off, 64);
            if (lane >= off) v += y;
        }
        if (lane == 63) wtot[wav] = v;
        __syncthreads();
        int wbase = 0;
        #pragma unroll
        for (int w = 0; w < 4; ++w) wbase += (w < wav) ? wtot[w] : 0;
        int run = wbase + v - tsum;
        #pragma unroll
        for (int q = 0; q < 4; ++q) {
            if (eb + q < NB) lstart[eb + q] = run;
            run += loc[q];
        }
    }
    __syncthreads();

    for (int b = t; b < NB; b += 256) {
        int c = hist[b];
        if (c > 0) gbase[b] = atomicAdd(&cursor[b], c);
        hist[b] = lstart[b];
    }
    __syncthreads();

    for (int i = t; i < ne; i += 256) {
        int d = dst[base + i];
        int s = src[base + i];
        int b = d >> BSHIFT;
        int pos = atomicAdd(&hist[b], 1);
        sorted[pos] = ((unsigned int)(d & (BNODES - 1)) << 20) | (unsigned int)s;
        bid[pos] = (unsigned short)b;
    }
    __syncthreads();

    for (int i = t; i < ne; i += 256) {
        int b = bid[i];
        binned[gbase[b] + (i - lstart[b])] = sorted[i];
    }
}

// ---------------- per-bucket CSR build ----------------

__global__ __launch_bounds__(256) void k_build(
    const unsigned int* __restrict__ binned, const int* __restrict__ bstart,
    int* __restrict__ csr, int* __restrict__ offs, int* __restrict__ ends,
    float* __restrict__ dinv, int n) {
    __shared__ int cnt[BNODES];
    __shared__ int lcur[BNODES];
    __shared__ int excl[BNODES];
    const int b = blockIdx.x;
    const int t = threadIdx.x;
    const int lane = t & 63, wav = t >> 6;
    const int s0 = bstart[b], s1 = bstart[b + 1];
    const int ne = s1 - s0;

    if (t < BNODES) cnt[t] = 0;
    __syncthreads();
    for (int i = t; i < ne; i += 256)
        atomicAdd(&cnt[(binned[s0 + i] >> 20) & (BNODES - 1)], 1);
    __syncthreads();

    if (wav == 0) {
        int c0 = cnt[2 * lane], c1 = cnt[2 * lane + 1];
        int v = c0 + c1;
        #pragma unroll
        for (int off = 1; off < 64; off <<= 1) {
            int y = __shfl_up(v, off, 64);
            if (lane >= off) v += y;
        }
        int ex = v - c0 - c1;
        excl[2 * lane] = ex;
        excl[2 * lane + 1] = ex + c0;
        lcur[2 * lane] = ex;
        lcur[2 * lane + 1] = ex + c0;
    }
    __syncthreads();

    if (t < BNODES) {
        int node = b * BNODES + t;
        if (node < n) {
            int deg = cnt[t] + 1;  // + self loop
            dinv[node] = rsqrtf((float)deg);
            int o = s0 + excl[t];
            offs[node] = o;
            ends[node] = o + cnt[t];
        }
    }
    __syncthreads();

    for (int i = t; i < ne; i += 256) {
        unsigned int v = binned[s0 + i];
        int dlow = (v >> 20) & (BNODES - 1);
        int p = atomicAdd(&lcur[dlow], 1);
        csr[s0 + p] = (int)(v & 0xFFFFFu);
    }
}

// ---------------- GEMM1: h1s[n][c] = bf16( dinv[n] * sum_k x[n][k]*W1[k][c] ) ----------
// One wave per row, barrier-free; W1 in 128 VGPRs; shuffle-butterfly reduce;
// 2-deep row prefetch. Output packed bf16 pairs (8 uints/row).

__global__ __launch_bounds__(256, 2) void k_gemm1(
    const float* __restrict__ x, const float* __restrict__ W1,
    const float* __restrict__ dinv, unsigned int* __restrict__ h1s, int n) {
    const int lane = threadIdx.x & 63;
    const int wav = threadIdx.x >> 6;

    float wA[4][16], wB[4][16];
    const float4* W1v = (const float4*)W1;
    #pragma unroll
    for (int j = 0; j < 4; ++j) {
        #pragma unroll
        for (int q = 0; q < 4; ++q) {
            float4 wa = W1v[(4 * lane + j) * 4 + q];
            wA[j][4 * q + 0] = wa.x; wA[j][4 * q + 1] = wa.y;
            wA[j][4 * q + 2] = wa.z; wA[j][4 * q + 3] = wa.w;
            float4 wb = W1v[(256 + 4 * lane + j) * 4 + q];
            wB[j][4 * q + 0] = wb.x; wB[j][4 * q + 1] = wb.y;
            wB[j][4 * q + 2] = wb.z; wB[j][4 * q + 3] = wb.w;
        }
    }

    const float4* xv = (const float4*)x;
    const int stride = gridDim.x * 4;

    auto process = [&](float4 p0, float4 p1, int r) {
        float part[16];
        #pragma unroll
        for (int c = 0; c < 16; ++c) part[c] = 0.f;
        float av[8] = {p0.x, p0.y, p0.z, p0.w, p1.x, p1.y, p1.z, p1.w};
        #pragma unroll
        for (int j = 0; j < 4; ++j) {
            #pragma unroll
            for (int c = 0; c < 16; ++c) {
                part[c] = fmaf(av[j], wA[j][c], part[c]);
                part[c] = fmaf(av[4 + j], wB[j][c], part[c]);
            }
        }
        const bool h5 = (lane & 32) != 0;
        float v8[8];
        #pragma unroll
        for (int j = 0; j < 8; ++j)
            v8[j] = (h5 ? part[j + 8] : part[j]) +
                    __shfl_xor(h5 ? part[j] : part[j + 8], 32, 64);
        const bool h4 = (lane & 16) != 0;
        float v4[4];
        #pragma unroll
        for (int j = 0; j < 4; ++j)
            v4[j] = (h4 ? v8[j + 4] : v8[j]) +
                    __shfl_xor(h4 ? v8[j] : v8[j + 4], 16, 64);
        const bool h3 = (lane & 8) != 0;
        float v2[2];
        #pragma unroll
        for (int j = 0; j < 2; ++j)
            v2[j] = (h3 ? v4[j + 2] : v4[j]) +
                    __shfl_xor(h3 ? v4[j] : v4[j + 2], 8, 64);
        const bool h2 = (lane & 4) != 0;
        float v1 = (h2 ? v2[1] : v2[0]) +
                   __shfl_xor(h2 ? v2[0] : v2[1], 4, 64);
        v1 += __shfl_xor(v1, 2, 64);
        v1 += __shfl_xor(v1, 1, 64);
        // every lane holds col (lane>>2); pair up cols (2p,2p+1) on lanes 8p
        float vnext = __shfl_down(v1, 4, 64);
        if ((lane & 7) == 0) {
            float di = dinv[r];
            h1s[(size_t)r * 8 + (lane >> 3)] = packbf(di * v1, di * vnext);
        }
    };

    int r0 = blockIdx.x * 4 + wav;
    int r1 = r0 + stride;
    float4 a0, a1, b0, b1;
    if (r0 < n) {
        a0 = xv[(size_t)r0 * 128 + lane];
        a1 = xv[(size_t)r0 * 128 + 64 + lane];
    }
    if (r1 < n) {
        b0 = xv[(size_t)r1 * 128 + lane];
        b1 = xv[(size_t)r1 * 128 + 64 + lane];
    }

    while (r0 < n) {
        float4 ca0 = a0, ca1 = a1;
        int pr = r0 + 2 * stride;
        if (pr < n) {
            a0 = xv[(size_t)pr * 128 + lane];
            a1 = xv[(size_t)pr * 128 + 64 + lane];
        }
        process(ca0, ca1, r0);
        if (r1 < n) {
            float4 cb0 = b0, cb1 = b1;
            int pr2 = r1 + 2 * stride;
            if (pr2 < n) {
                b0 = xv[(size_t)pr2 * 128 + lane];
                b1 = xv[(size_t)pr2 * 128 + 64 + lane];
            }
            process(cb0, cb1, r1);
        }
        r0 += 2 * stride;
        r1 += 2 * stride;
    }
}

// ---------------- gather1: 8 lanes/node, bf16x2 per lane, 4-wide MLP ----------------

__global__ __launch_bounds__(256) void k_gather1(
    const int* __restrict__ offs, const int* __restrict__ ends,
    const int* __restrict__ csr, const unsigned int* __restrict__ h1s,
    const float* __restrict__ dinv, const float* __restrict__ b1,
    unsigned int* __restrict__ hs2, int n) {
    int t = blockIdx.x * 256 + threadIdx.x;
    int node = t >> 3, p = t & 7;
    if (node >= n) return;
    int j = offs[node], e = ends[node];
    unsigned int su = h1s[(size_t)node * 8 + p];  // self loop
    float aL = bflo(su), aH = bfhi(su);
    float bL = 0.f, bH = 0.f, cL = 0.f, cH = 0.f, dL = 0.f, dH = 0.f;
    for (; j + 3 < e; j += 4) {
        int i0 = csr[j], i1 = csr[j + 1], i2 = csr[j + 2], i3 = csr[j + 3];
        unsigned int u0 = h1s[(size_t)i0 * 8 + p];
        unsigned int u1 = h1s[(size_t)i1 * 8 + p];
        unsigned int u2 = h1s[(size_t)i2 * 8 + p];
        unsigned int u3 = h1s[(size_t)i3 * 8 + p];
        aL += bflo(u0); aH += bfhi(u0);
        bL += bflo(u1); bH += bfhi(u1);
        cL += bflo(u2); cH += bfhi(u2);
        dL += bflo(u3); dH += bfhi(u3);
    }
    for (; j < e; ++j) {
        unsigned int u = h1s[(size_t)csr[j] * 8 + p];
        aL += bflo(u); aH += bfhi(u);
    }
    float sL = (aL + bL) + (cL + dL);
    float sH = (aH + bH) + (cH + dH);
    float di = dinv[node];
    float vL = fmaf(di, sL, b1[2 * p]);
    float vH = fmaf(di, sH, b1[2 * p + 1]);
    hs2[(size_t)node * 8 + p] = packbf(di * fmaxf(vL, 0.f), di * fmaxf(vH, 0.f));
}

// ---------------- fused gather2 + W2 + b2 + log_softmax ----------------

__global__ __launch_bounds__(256) void k_g2f(
    const int* __restrict__ offs, const int* __restrict__ ends,
    const int* __restrict__ csr, const unsigned int* __restrict__ hs2,
    const float* __restrict__ dinv, const float* __restrict__ W2,
    const float* __restrict__ b2, float* __restrict__ out, int n) {
    __shared__ float w2s[NF1 * NF2];
    __shared__ float b2s[NF2];
    __shared__ float agg[32][17];
    for (int i = threadIdx.x; i < NF1 * NF2; i += 256) w2s[i] = W2[i];
    if (threadIdx.x < NF2) b2s[threadIdx.x] = b2[threadIdx.x];

    int t = blockIdx.x * 256 + threadIdx.x;
    int node = t >> 3, p = t & 7;
    int g = threadIdx.x >> 3;
    float rL = 0.f, rH = 0.f;
    if (node < n) {
        int j = offs[node], e = ends[node];
        unsigned int su = hs2[(size_t)node * 8 + p];  // self loop
        float aL = bflo(su), aH = bfhi(su);
        float bL = 0.f, bH = 0.f, cL = 0.f, cH = 0.f, dL = 0.f, dH = 0.f;
        for (; j + 3 < e; j += 4) {
            int i0 = csr[j], i1 = csr[j + 1], i2 = csr[j + 2], i3 = csr[j + 3];
            unsigned int u0 = hs2[(size_t)i0 * 8 + p];
            unsigned int u1 = hs2[(size_t)i1 * 8 + p];
            unsigned int u2 = hs2[(size_t)i2 * 8 + p];
            unsigned int u3 = hs2[(size_t)i3 * 8 + p];
            aL += bflo(u0); aH += bfhi(u0);
            bL += bflo(u1); bH += bfhi(u1);
            cL += bflo(u2); cH += bfhi(u2);
            dL += bflo(u3); dH += bfhi(u3);
        }
        for (; j < e; ++j) {
            unsigned int u = hs2[(size_t)csr[j] * 8 + p];
            aL += bflo(u); aH += bfhi(u);
        }
        float di = dinv[node];
        rL = ((aL + bL) + (cL + dL)) * di;
        rH = ((aH + bH) + (cH + dH)) * di;
    }
    agg[g][2 * p] = rL;
    agg[g][2 * p + 1] = rH;
    __syncthreads();

    int wav = threadIdx.x >> 6, lane = threadIdx.x & 63;
    int nbase = blockIdx.x * 32 + wav * 8;
    #pragma unroll
    for (int q = 0; q < 8; ++q) {
        int nd = nbase + q;
        if (nd >= n) break;  // nd uniform across wave
        float av[16];
        #pragma unroll
        for (int k = 0; k < 16; ++k) av[k] = agg[wav * 8 + q][k];
        float d = -1e30f;
        if (lane < NF2) {
            d = b2s[lane];
            #pragma unroll
            for (int k = 0; k < 16; ++k) d = fmaf(av[k], w2s[k * NF2 + lane], d);
        }
        float m = d;
        #pragma unroll
        for (int off = 32; off; off >>= 1) m = fmaxf(m, __shfl_xor(m, off, 64));
        float e2 = (lane < NF2) ? __expf(d - m) : 0.f;
        float ssum = e2;
        #pragma unroll
        for (int off = 32; off; off >>= 1) ssum += __shfl_xor(ssum, off, 64);
        float ls = __logf(ssum);
        if (lane < NF2) out[(size_t)nd * NF2 + lane] = d - m - ls;
    }
}

// ---------------- launch ----------------

extern "C" void kernel_launch(void* const* d_in, const int* in_sizes, int n_in,
                              void* d_out, int out_size, void* d_ws, size_t ws_size,
                              hipStream_t stream) {
    const float* x  = (const float*)d_in[0];
    const int*   ei = (const int*)d_in[1];
    const float* W1 = (const float*)d_in[2];
    const float* b1 = (const float*)d_in[3];
    const float* W2 = (const float*)d_in[4];
    const float* b2 = (const float*)d_in[5];
    float* out = (float*)d_out;

    const int N = in_sizes[0] / NF0;  // 100000
    const int E = in_sizes[1] / 2;    // 3200000
    const int NB = (N + BNODES - 1) / BNODES;  // 782
    const int* src = ei;
    const int* dst = ei + E;

    char* ws = (char*)d_ws;
    size_t off = 0;
    auto alloc = [&](size_t bytes) -> void* {
        void* p = ws + off;
        off = (off + bytes + 255) & ~(size_t)255;
        return p;
    };
    int*   bhist  = (int*)alloc((size_t)NB * 4);
    int*   bstart = (int*)alloc((size_t)(NB + 1) * 4);
    int*   cursor = (int*)alloc((size_t)NB * 4);
    unsigned int* binned = (unsigned int*)alloc((size_t)E * 4);
    int*   csr    = (int*)alloc((size_t)E * 4);
    int*   offs   = (int*)alloc((size_t)N * 4);
    int*   ends   = (int*)alloc((size_t)N * 4);
    float* dinv   = (float*)alloc((size_t)N * 4);
    // binned dead after k_build: reuse for bf16 h1s/hs2 (3.2MB each)
    unsigned int* h1s = binned;
    unsigned int* hs2 = binned + (size_t)N * 8;

    const int eb = (E + CHUNK - 1) / CHUNK;  // 391
    const size_t histBytes = (size_t)NB * 4;

    k_zero   <<<(NB + 255) / 256, 256, 0, stream>>>(bhist, NB);
    k_hist   <<<512, 256, histBytes, stream>>>(dst, bhist, E, NB);
    k_scan   <<<1, 1024, 0, stream>>>(bhist, bstart, cursor, NB);
    k_binsort<<<eb, 256, 3 * histBytes, stream>>>(src, dst, cursor, binned, E, NB);
    k_build  <<<NB, 256, 0, stream>>>(binned, bstart, csr, offs, ends, dinv, N);
    k_gemm1  <<<1024, 256, 0, stream>>>(x, W1, dinv, h1s, N);
    k_gather1<<<(N * 8 + 255) / 256, 256, 0, stream>>>(offs, ends, csr, h1s, dinv, b1, hs2, N);
    k_g2f    <<<(N * 8 + 255) / 256, 256, 0, stream>>>(offs, ends, csr, hs2, dinv, W2, b2, out, N);
}